// Round 8
// baseline (273.573 us; speedup 1.0000x reference)
//
#include <hip/hip_runtime.h>

#define TOKENS 65536
#define DIM 64
#define NCODE 1024
#define MARGIN 2.5e-4f
#define FLAG_CAP 8192

#define OUT_IDX_OFF ((size_t)TOKENS * DIM)          // 4194304
#define OUT_LOSS_OFF (OUT_IDX_OFF + TOKENS)         // 4259840

// ws layout (bytes):
#define WS_LOSS   0        // double
#define WS_FLAGC  8        // uint
#define WS_DONE   12       // uint
#define WS_BNORM  16       // f32[1024]      -> 4112
#define WS_CHI    4224     // ushort[65536]  -> 135296 (codebook -2c hi, A-frag)
#define WS_CLO    135296   // ushort[65536]  -> 266368 (codebook -2c lo)
#define WS_PACKED 266368   // u64[8192]      -> 331904 (per-flagged argmin)
#define WS_FLAGS  331904   // int[8192]      -> 364672

typedef __attribute__((ext_vector_type(8))) short short8;
typedef __attribute__((ext_vector_type(4))) float f32x4;

// ---------------------------------------------------------------------------
// numpy-bitwise f32 sum-of-squares — VERIFIED absmax=0 (round 2). Do not touch.
// ---------------------------------------------------------------------------
__device__ __forceinline__ float np_sumsq64(const float* __restrict__ x) {
#pragma clang fp contract(off)
    float r[8];
#pragma unroll
    for (int j = 0; j < 8; ++j) r[j] = x[j] * x[j];
#pragma unroll
    for (int i = 8; i < 64; i += 8) {
#pragma unroll
        for (int j = 0; j < 8; ++j) {
            float sq = x[i + j] * x[i + j];
            r[j] = r[j] + sq;
        }
    }
    return ((r[0] + r[1]) + (r[2] + r[3])) + ((r[4] + r[5]) + (r[6] + r[7]));
}

// ---------------------------------------------------------------------------
// Prep: codebook -> bf16 hi/lo A-frags of (-2*C) + bnorm; zero-inits the
// control words (loss/flagc/done) so no memset nodes are needed.
// ---------------------------------------------------------------------------
__global__ __launch_bounds__(256) void vq_prep(
    const float* __restrict__ cb, unsigned short* __restrict__ chi,
    unsigned short* __restrict__ clo, float* __restrict__ bnorm,
    double* __restrict__ loss_sum, unsigned int* __restrict__ flag_count,
    unsigned int* __restrict__ done) {
    int tid = blockIdx.x * 256 + threadIdx.x;   // 0..65535
    if (tid == 0) { *loss_sum = 0.0; *flag_count = 0u; *done = 0u; }
    int j = tid & 7;
    int L = (tid >> 3) & 63;
    int cs = tid >> 9;          // 0..127
    int s = cs & 1, c = cs >> 1;
    int code = c * 16 + (L & 15);
    int d = s * 32 + (L >> 4) * 8 + j;
    float v = -2.0f * cb[(size_t)code * DIM + d];
    unsigned int b = __float_as_uint(v);
    chi[tid] = (unsigned short)(b >> 16);                       // truncation split
    float hf = __uint_as_float(b & 0xFFFF0000u);
    float lo;
    {
#pragma clang fp contract(off)
        lo = v - hf;                                            // exact in f32
    }
    clo[tid] = (unsigned short)(__float_as_uint(lo) >> 16);

    if (tid < NCODE) bnorm[tid] = np_sumsq64(cb + (size_t)tid * DIM);
}

__device__ __forceinline__ void top2_merge(float& a1, float& a2, int& ai,
                                           float b1, float b2, int bi) {
    float n1 = fminf(a1, b1);
    float n2 = fminf(fmaxf(a1, b1), fminf(a2, b2));
    ai = (b1 < a1) ? bi : ai;   // ties keep a (exact ties get flagged anyway)
    a1 = n1; a2 = n2;
}

// ---------------------------------------------------------------------------
// Fast screen, v4. Block = 4 waves, 64 tokens, grid 1024 (4 blocks/CU).
// Wave w: token pair-tile tp=w>>1 (32 tokens, 2 MFMA col-tiles) x code half
// h=w&1 (32 chunks of 16 codes). Per-wave A-traffic 128 KB; per-CU delivery
// ~2 MB. bnorm served from LDS (off the L1 stream). Cross-wave-pair top-2
// merge via LDS (r6-verified). MFMA chain + numerics identical to verified
// rounds; WRITE_SIZE is the spill detector (expect ~16 MB).
// ---------------------------------------------------------------------------
__global__ __launch_bounds__(256, 4) void vq_fast(
    const float* __restrict__ z, const float* __restrict__ cb,
    const unsigned short* __restrict__ cfrag_hi,
    const unsigned short* __restrict__ cfrag_lo,
    const float* __restrict__ bnorm, float* __restrict__ out,
    unsigned int* __restrict__ flag_count, int* __restrict__ flag_list,
    unsigned long long* __restrict__ packed_min,
    double* __restrict__ loss_sum, unsigned int flag_cap) {
    __shared__ float bn_lds[NCODE];
    __shared__ float sm1[4][32];
    __shared__ float sm2[4][32];
    __shared__ int   sbi[4][32];
    __shared__ int   s_best[64];
    __shared__ int   s_flag[64];

    const int tid = threadIdx.x;
    const int lane = tid & 63;
    const int w = tid >> 6;
    const int half = w & 1;                  // code half
    const int tp = w >> 1;                   // token pair-tile
    const int t0 = blockIdx.x * 64;
    const int tw = t0 + tp * 32;             // this wave's 32 tokens
    const int col = lane & 15;
    const int quad = lane >> 4;

    // stage bnorm into LDS (4 KB)
    ((float4*)bn_lds)[tid] = ((const float4*)bnorm)[tid];

    // token B-fragments (bf16 hi/lo), 2 tiles x 2 K-steps, in registers
    short8 zhi[2][2], zlo[2][2];
#pragma unroll
    for (int tt = 0; tt < 2; ++tt) {
#pragma unroll
        for (int s = 0; s < 2; ++s) {
            const float* zp = z + (size_t)(tw + tt * 16 + col) * DIM + s * 32 + quad * 8;
            float4 f0 = ((const float4*)zp)[0];
            float4 f1 = ((const float4*)zp)[1];
            float f[8] = {f0.x, f0.y, f0.z, f0.w, f1.x, f1.y, f1.z, f1.w};
            short8 h, l;
#pragma unroll
            for (int j = 0; j < 8; ++j) {
                unsigned int b = __float_as_uint(f[j]);
                h[j] = (short)(b >> 16);
                float hf = __uint_as_float(b & 0xFFFF0000u);
                float lo;
                {
#pragma clang fp contract(off)
                    lo = f[j] - hf;
                }
                l[j] = (short)(__float_as_uint(lo) >> 16);
            }
            zhi[tt][s] = h; zlo[tt][s] = l;
        }
    }
    __syncthreads();   // bn_lds ready

    float m1[2] = {3.0e38f, 3.0e38f};
    float m2[2] = {3.0e38f, 3.0e38f};
    int bi[2] = {0, 0};

    const short8* CH = (const short8*)cfrag_hi;
    const short8* CL = (const short8*)cfrag_lo;
    const int koff = quad * 4;

    int c = half * 32;
    short8 ch0 = CH[(c * 2 + 0) * 64 + lane];
    short8 ch1 = CH[(c * 2 + 1) * 64 + lane];
    short8 cl0 = CL[(c * 2 + 0) * 64 + lane];
    short8 cl1 = CL[(c * 2 + 1) * 64 + lane];

    for (int m = 0; m < 32; ++m) {
        const int cn = (m < 31) ? c + 1 : c;   // last iter: redundant reload
        short8 nh0 = CH[(cn * 2 + 0) * 64 + lane];
        short8 nh1 = CH[(cn * 2 + 1) * 64 + lane];
        short8 nl0 = CL[(cn * 2 + 0) * 64 + lane];
        short8 nl1 = CL[(cn * 2 + 1) * 64 + lane];

        const int cbase = c * 16 + koff;
        const f32x4 bn = *(const f32x4*)&bn_lds[cbase];
#pragma unroll
        for (int tt = 0; tt < 2; ++tt) {
            f32x4 acc = bn;
            acc = __builtin_amdgcn_mfma_f32_16x16x32_bf16(ch0, zhi[tt][0], acc, 0, 0, 0);
            acc = __builtin_amdgcn_mfma_f32_16x16x32_bf16(cl0, zhi[tt][0], acc, 0, 0, 0);
            acc = __builtin_amdgcn_mfma_f32_16x16x32_bf16(ch0, zlo[tt][0], acc, 0, 0, 0);
            acc = __builtin_amdgcn_mfma_f32_16x16x32_bf16(ch1, zhi[tt][1], acc, 0, 0, 0);
            acc = __builtin_amdgcn_mfma_f32_16x16x32_bf16(cl1, zhi[tt][1], acc, 0, 0, 0);
            acc = __builtin_amdgcn_mfma_f32_16x16x32_bf16(ch1, zlo[tt][1], acc, 0, 0, 0);
#pragma unroll
            for (int i = 0; i < 4; ++i) {
                float u = acc[i];
                float om1 = m1[tt];
                bool lt = u < om1;
                float fm = fminf(m2[tt], u);
                m2[tt] = lt ? om1 : fm;
                m1[tt] = lt ? u : om1;
                bi[tt] = lt ? (cbase + i) : bi[tt];
            }
        }
        ch0 = nh0; ch1 = nh1; cl0 = nl0; cl1 = nl1;
        c = cn;
    }

    // in-wave quad merge (lanes l, l^16, l^32, l^48 share a token column)
#pragma unroll
    for (int tt = 0; tt < 2; ++tt) {
        float a1 = m1[tt], a2 = m2[tt];
        int ai = bi[tt];
        {
            float o1 = __shfl_xor(a1, 16); float o2 = __shfl_xor(a2, 16);
            int oi = __shfl_xor(ai, 16);
            top2_merge(a1, a2, ai, o1, o2, oi);
        }
        {
            float o1 = __shfl_xor(a1, 32); float o2 = __shfl_xor(a2, 32);
            int oi = __shfl_xor(ai, 32);
            top2_merge(a1, a2, ai, o1, o2, oi);
        }
        if (quad == 0) {
            sm1[w][tt * 16 + col] = a1;
            sm2[w][tt * 16 + col] = a2;
            sbi[w][tt * 16 + col] = ai;
        }
    }
    __syncthreads();

    // merge the two code halves per token (wave pair 2*tp, 2*tp+1)
    if (tid < 64) {
        const int i = tid & 31;
        const int w0 = (tid >> 5) * 2;
        float M1 = sm1[w0][i], M2 = sm2[w0][i];
        int B = sbi[w0][i];
        top2_merge(M1, M2, B, sm1[w0 + 1][i], sm2[w0 + 1][i], sbi[w0 + 1][i]);
        int fl = (M2 - M1) < MARGIN;
        if (fl) {
            unsigned int pos = atomicAdd(flag_count, 1u);
            if (pos >= flag_cap) fl = 0;
            else {
                flag_list[pos] = t0 + tid;
                packed_min[pos] = ~0ull;       // lazy init (replaces memset node)
            }
        }
        s_best[tid] = B;
        s_flag[tid] = fl;
    }
    __syncthreads();

    // epilogue: 4 threads per token, 16 floats each (r5-verified); flagged deferred
    const int et = tid >> 2, eq = tid & 3;
    float loss_t = 0.0f;
    if (!s_flag[et]) {
        const int B = s_best[et];
        const float4* cq  = (const float4*)(cb + (size_t)B * DIM + eq * 16);
        const float4* zq4 = (const float4*)(z + (size_t)(t0 + et) * DIM + eq * 16);
        float4* o4 = (float4*)(out + (size_t)(t0 + et) * DIM + eq * 16);
#pragma unroll
        for (int jj = 0; jj < 4; ++jj) {
#pragma clang fp contract(off)
            float4 cc = cq[jj];
            float4 zz = zq4[jj];
            float d0 = cc.x - zz.x, d1 = cc.y - zz.y;
            float d2 = cc.z - zz.z, d3 = cc.w - zz.w;
            float4 o;
            o.x = zz.x + d0; o.y = zz.y + d1;
            o.z = zz.z + d2; o.w = zz.w + d3;
            o4[jj] = o;
            loss_t = __fmaf_rn(d0, d0, loss_t);
            loss_t = __fmaf_rn(d1, d1, loss_t);
            loss_t = __fmaf_rn(d2, d2, loss_t);
            loss_t = __fmaf_rn(d3, d3, loss_t);
        }
        if (eq == 0) out[OUT_IDX_OFF + t0 + et] = (float)B;
    }
#pragma unroll
    for (int off = 32; off > 0; off >>= 1)
        loss_t += __shfl_down(loss_t, off);
    if (lane == 0) atomicAdd(loss_sum, (double)loss_t);
}

__device__ __forceinline__ unsigned long long shfl_down_u64(unsigned long long v, int off) {
    unsigned int lo = (unsigned int)v, hi = (unsigned int)(v >> 32);
    lo = __shfl_down(lo, off);
    hi = __shfl_down(hi, off);
    return ((unsigned long long)hi << 32) | lo;
}

// ---------------------------------------------------------------------------
// Exact numpy-bitwise pass (code-stationary) — verified absmax=0 rounds 6-7.
// ---------------------------------------------------------------------------
__global__ __launch_bounds__(256) void vq_exact_min(
    const float* __restrict__ z, const float* __restrict__ cb,
    const float* __restrict__ bnorm,
    const unsigned int* __restrict__ flag_count,
    const int* __restrict__ flag_list,
    unsigned long long* __restrict__ packed_min, unsigned int flag_cap) {
    __shared__ float zsh[64 * 68];
    __shared__ float szs[64];

    const int tid = threadIdx.x;
    const int w = tid >> 6;
    const int lane = tid & 63;
    unsigned int count = *flag_count;
    if (count > flag_cap) count = flag_cap;
    const unsigned int ngroups = (count + 63) >> 6;

    const int q = blockIdx.x & 3;
    const unsigned int g = blockIdx.x >> 2;          // 0..127; ngroups <= 128
    if (g >= ngroups) return;

    const int k = q * 256 + w * 64 + lane;           // this lane's code

    float row[DIM];
    {
        const float4* c4 = (const float4*)(cb + (size_t)k * DIM);
#pragma unroll
        for (int j = 0; j < 16; ++j) {
            float4 v = c4[j];
            row[4 * j + 0] = v.x; row[4 * j + 1] = v.y;
            row[4 * j + 2] = v.z; row[4 * j + 3] = v.w;
        }
    }
    const float bnk = bnorm[k];

    {
        const int i = tid >> 2, part = tid & 3;
        const unsigned int li = g * 64 + i;
        if (li < count) {
            const int t = flag_list[li];
            const float4* zp = (const float4*)(z + (size_t)t * DIM + part * 16);
            float4* dst = (float4*)(zsh + i * 68 + part * 16);
#pragma unroll
            for (int e = 0; e < 4; ++e) dst[e] = zp[e];
        }
    }
    __syncthreads();
    if (tid < 64) szs[tid] = np_sumsq64(zsh + tid * 68);
    __syncthreads();

    for (int tt = 0; tt < 64; ++tt) {
        const unsigned int li = g * 64 + tt;
        const float* zp = zsh + tt * 68;             // wave-uniform -> broadcast
        float l16[16];
#pragma unroll
        for (int g2 = 0; g2 < 4; ++g2) {
            float4 v0 = ((const float4*)(zp + 4 * g2))[0];
            float4 v1 = ((const float4*)(zp + 16 + 4 * g2))[0];
            float4 v2 = ((const float4*)(zp + 32 + 4 * g2))[0];
            float4 v3 = ((const float4*)(zp + 48 + 4 * g2))[0];
            float a0[4] = {v0.x, v0.y, v0.z, v0.w};
            float a1[4] = {v1.x, v1.y, v1.z, v1.w};
            float a2[4] = {v2.x, v2.y, v2.z, v2.w};
            float a3[4] = {v3.x, v3.y, v3.z, v3.w};
#pragma unroll
            for (int e = 0; e < 4; ++e) {
#pragma clang fp contract(off)
                int jj = 4 * g2 + e;
                float acc = a3[e] * row[48 + jj];
                acc = __fmaf_rn(a2[e], row[32 + jj], acc);
                acc = __fmaf_rn(a1[e], row[16 + jj], acc);
                acc = __fmaf_rn(a0[e], row[jj],      acc);
                l16[jj] = acc;
            }
        }
        float e_np;
        {
#pragma clang fp contract(off)
#pragma unroll
            for (int jj = 0; jj < 8; ++jj) l16[jj] = l16[jj] + l16[jj + 8];
#pragma unroll
            for (int jj = 0; jj < 4; ++jj) l16[jj] = l16[jj] + l16[jj + 4];
            l16[0] = l16[0] + l16[2];
            l16[1] = l16[1] + l16[3];
            e_np = l16[0] + l16[1];
        }
        float dd;
        {
#pragma clang fp contract(off)
            float t1 = szs[tt] + bnk;
            float mm = 2.0f * e_np;
            dd = t1 - mm;
        }
        unsigned long long pk =
            ((unsigned long long)__float_as_uint(dd) << 10) | (unsigned int)k;
#pragma unroll
        for (int off = 32; off > 0; off >>= 1) {
            unsigned long long o = shfl_down_u64(pk, off);
            pk = (o < pk) ? o : pk;
        }
        if (lane == 0 && li < count)
            atomicMin(&packed_min[li], pk);
    }
}

// flagged-token outputs + fused final loss write (done-counter; last block)
__global__ __launch_bounds__(256) void vq_finish(
    const float* __restrict__ z, const float* __restrict__ cb,
    float* __restrict__ out, const unsigned int* __restrict__ flag_count,
    const int* __restrict__ flag_list,
    const unsigned long long* __restrict__ packed_min,
    double* __restrict__ loss_sum, unsigned int* __restrict__ done,
    unsigned int flag_cap) {
    const int lane = threadIdx.x & 63;
    unsigned int count = *flag_count;
    if (count > flag_cap) count = flag_cap;
    const unsigned int gw = blockIdx.x * 4 + (threadIdx.x >> 6);
    const unsigned int NW = gridDim.x * 4;

    for (unsigned int li = gw; li < count; li += NW) {
        const int t = flag_list[li];
        const int best = (int)(packed_min[li] & 1023ull);
        const float zl = z[(size_t)t * DIM + lane];
        const float zq = cb[(size_t)best * DIM + lane];
        float d, o;
        {
#pragma clang fp contract(off)
            d = zq - zl;
            o = zl + d;
        }
        out[(size_t)t * DIM + lane] = o;
        float l2 = d * d;
#pragma unroll
        for (int off = 32; off > 0; off >>= 1)
            l2 += __shfl_down(l2, off);
        if (lane == 0) {
            out[OUT_IDX_OFF + t] = (float)best;
            atomicAdd(loss_sum, (double)l2);
        }
    }

    __threadfence();
    __syncthreads();
    if (threadIdx.x == 0) {
        unsigned int old = atomicAdd(done, 1u);
        if (old == gridDim.x - 1) {
            double L = atomicAdd(loss_sum, 0.0);   // coherent read-through
            out[OUT_LOSS_OFF] = (float)(2.0 * L / (double)((size_t)TOKENS * DIM));
        }
    }
}

extern "C" void kernel_launch(void* const* d_in, const int* in_sizes, int n_in,
                              void* d_out, int out_size, void* d_ws, size_t ws_size,
                              hipStream_t stream) {
    const float* z  = (const float*)d_in[0];   // [8,8192,64] f32
    const float* cb = (const float*)d_in[1];   // [1024,64] f32
    float* out = (float*)d_out;

    char* ws = (char*)d_ws;
    double* loss_sum = (double*)(ws + WS_LOSS);
    unsigned int* flag_count = (unsigned int*)(ws + WS_FLAGC);
    unsigned int* done = (unsigned int*)(ws + WS_DONE);
    float* bnorm = (float*)(ws + WS_BNORM);
    unsigned short* chi = (unsigned short*)(ws + WS_CHI);
    unsigned short* clo = (unsigned short*)(ws + WS_CLO);
    unsigned long long* packed = (unsigned long long*)(ws + WS_PACKED);
    int* flag_list = (int*)(ws + WS_FLAGS);

    unsigned int cap = 0;
    if (ws_size > WS_FLAGS + 4) {
        size_t c = (ws_size - WS_FLAGS) / 4;
        cap = (c > FLAG_CAP) ? FLAG_CAP : (unsigned int)c;
    }

    vq_prep<<<dim3(256), dim3(256), 0, stream>>>(
        cb, chi, clo, bnorm, loss_sum, flag_count, done);
    vq_fast<<<dim3(TOKENS / 64), dim3(256), 0, stream>>>(
        z, cb, chi, clo, bnorm, out, flag_count, flag_list, packed, loss_sum, cap);
    vq_exact_min<<<dim3(512), dim3(256), 0, stream>>>(
        z, cb, bnorm, flag_count, flag_list, packed, cap);
    vq_finish<<<dim3(128), dim3(256), 0, stream>>>(
        z, cb, out, flag_count, flag_list, packed, loss_sum, done, cap);
}

// Round 9
// 261.658 us; speedup vs baseline: 1.0455x; 1.0455x over previous
//
#include <hip/hip_runtime.h>

#define TOKENS 65536
#define DIM 64
#define NCODE 1024
#define MARGIN 2.5e-4f
#define FLAG_CAP 8192

#define OUT_IDX_OFF ((size_t)TOKENS * DIM)          // 4194304
#define OUT_LOSS_OFF (OUT_IDX_OFF + TOKENS)         // 4259840

// ws layout (bytes):
#define WS_LOSS   0        // double
#define WS_FLAGC  8        // uint
#define WS_DONE   12       // uint
#define WS_BNORM  16       // f32[1024]      -> 4112
#define WS_CHI    4224     // ushort[65536]  -> 135296 (codebook -2c hi, A-frag)
#define WS_CLO    135296   // ushort[65536]  -> 266368 (codebook -2c lo)
#define WS_PACKED 266368   // u64[8192]      -> 331904 (per-flagged argmin)
#define WS_FLAGS  331904   // int[8192]      -> 364672

typedef __attribute__((ext_vector_type(8))) short short8;
typedef __attribute__((ext_vector_type(4))) float f32x4;

// ---------------------------------------------------------------------------
// numpy-bitwise f32 sum-of-squares — VERIFIED absmax=0 (round 2). Do not touch.
// ---------------------------------------------------------------------------
__device__ __forceinline__ float np_sumsq64(const float* __restrict__ x) {
#pragma clang fp contract(off)
    float r[8];
#pragma unroll
    for (int j = 0; j < 8; ++j) r[j] = x[j] * x[j];
#pragma unroll
    for (int i = 8; i < 64; i += 8) {
#pragma unroll
        for (int j = 0; j < 8; ++j) {
            float sq = x[i + j] * x[i + j];
            r[j] = r[j] + sq;
        }
    }
    return ((r[0] + r[1]) + (r[2] + r[3])) + ((r[4] + r[5]) + (r[6] + r[7]));
}

// ---------------------------------------------------------------------------
// Prep: codebook -> bf16 hi/lo A-frags of (-2*C) + bnorm; zero-inits control
// words (loss/flagc/done). Verified absmax=0 rounds 4-8.
// ---------------------------------------------------------------------------
__global__ __launch_bounds__(256) void vq_prep(
    const float* __restrict__ cb, unsigned short* __restrict__ chi,
    unsigned short* __restrict__ clo, float* __restrict__ bnorm,
    double* __restrict__ loss_sum, unsigned int* __restrict__ flag_count,
    unsigned int* __restrict__ done) {
    int tid = blockIdx.x * 256 + threadIdx.x;   // 0..65535
    if (tid == 0) { *loss_sum = 0.0; *flag_count = 0u; *done = 0u; }
    int j = tid & 7;
    int L = (tid >> 3) & 63;
    int cs = tid >> 9;          // 0..127
    int s = cs & 1, c = cs >> 1;
    int code = c * 16 + (L & 15);
    int d = s * 32 + (L >> 4) * 8 + j;
    float v = -2.0f * cb[(size_t)code * DIM + d];
    unsigned int b = __float_as_uint(v);
    chi[tid] = (unsigned short)(b >> 16);                       // truncation split
    float hf = __uint_as_float(b & 0xFFFF0000u);
    float lo;
    {
#pragma clang fp contract(off)
        lo = v - hf;                                            // exact in f32
    }
    clo[tid] = (unsigned short)(__float_as_uint(lo) >> 16);

    if (tid < NCODE) bnorm[tid] = np_sumsq64(cb + (size_t)tid * DIM);
}

__device__ __forceinline__ void top2_merge(float& a1, float& a2, int& ai,
                                           float b1, float b2, int bi) {
    float n1 = fminf(a1, b1);
    float n2 = fminf(fmaxf(a1, b1), fminf(a2, b2));
    ai = (b1 < a1) ? bi : ai;   // ties keep a (exact ties get flagged anyway)
    a1 = n1; a2 = n2;
}

// ---------------------------------------------------------------------------
// Fast screen, v5: LDS-staged fragments (GEMM-style double buffer).
// Block = 4 waves x 32 tokens = 128 tokens; each wave scans ALL 1024 codes.
// A-fragments staged into LDS per block in 8 groups of 8 chunks (16KB hi +
// 16KB lo per buffer, x2 buffers) -> global fragment traffic drops 4x and
// waves read fragments via conflict-free ds_read_b128 instead of the
// L1-miss-limited per-lane global path (r7/r8: ~6.7 TB/s aggregate cap).
// Loads for group g+1 issue before compute of g; one barrier per group.
// MFMA chain + all numerics identical to verified rounds 4-8.
// ---------------------------------------------------------------------------
__global__ __launch_bounds__(256, 2) void vq_fast(
    const float* __restrict__ z, const float* __restrict__ cb,
    const unsigned short* __restrict__ cfrag_hi,
    const unsigned short* __restrict__ cfrag_lo,
    const float* __restrict__ bnorm, float* __restrict__ out,
    unsigned int* __restrict__ flag_count, int* __restrict__ flag_list,
    unsigned long long* __restrict__ packed_min,
    double* __restrict__ loss_sum, unsigned int flag_cap) {
    __shared__ short8 sh_hi[2][1024];   // [buf][(chunk*2+step)*64 + lane], 16KB each
    __shared__ short8 sh_lo[2][1024];
    __shared__ float bn_lds[NCODE];
    __shared__ int s_best[128];
    __shared__ int s_flag[128];

    const int tid = threadIdx.x;
    const int lane = tid & 63;
    const int w = tid >> 6;
    const int t0 = blockIdx.x * 128;
    const int tw = t0 + w * 32;              // this wave's 32 tokens
    const int col = lane & 15;
    const int quad = lane >> 4;

    // stage bnorm into LDS (4 KB)
    ((float4*)bn_lds)[tid] = ((const float4*)bnorm)[tid];

    // token B-fragments (bf16 hi/lo), 2 tiles x 2 K-steps, in registers
    short8 zhi[2][2], zlo[2][2];
#pragma unroll
    for (int tt = 0; tt < 2; ++tt) {
#pragma unroll
        for (int s = 0; s < 2; ++s) {
            const float* zp = z + (size_t)(tw + tt * 16 + col) * DIM + s * 32 + quad * 8;
            float4 f0 = ((const float4*)zp)[0];
            float4 f1 = ((const float4*)zp)[1];
            float f[8] = {f0.x, f0.y, f0.z, f0.w, f1.x, f1.y, f1.z, f1.w};
            short8 h, l;
#pragma unroll
            for (int j = 0; j < 8; ++j) {
                unsigned int b = __float_as_uint(f[j]);
                h[j] = (short)(b >> 16);
                float hf = __uint_as_float(b & 0xFFFF0000u);
                float lo;
                {
#pragma clang fp contract(off)
                    lo = f[j] - hf;
                }
                l[j] = (short)(__float_as_uint(lo) >> 16);
            }
            zhi[tt][s] = h; zlo[tt][s] = l;
        }
    }

    const short8* CH = (const short8*)cfrag_hi;   // 4096 short8 total (64 chunks)
    const short8* CL = (const short8*)cfrag_lo;

    // stage group 0 (8 chunks = 1024 short8 per array; 4 per thread)
    short8 rh[4], rl[4];
#pragma unroll
    for (int r = 0; r < 4; ++r) {
        rh[r] = CH[tid + r * 256];
        rl[r] = CL[tid + r * 256];
    }
#pragma unroll
    for (int r = 0; r < 4; ++r) {
        sh_hi[0][tid + r * 256] = rh[r];
        sh_lo[0][tid + r * 256] = rl[r];
    }
    __syncthreads();

    float m1[2] = {3.0e38f, 3.0e38f};
    float m2[2] = {3.0e38f, 3.0e38f};
    int bi[2] = {0, 0};
    const int koff = quad * 4;

    for (int g = 0; g < 8; ++g) {
        const int buf = g & 1;
        // issue next group's global loads first (full compute time to land)
        if (g < 7) {
#pragma unroll
            for (int r = 0; r < 4; ++r) {
                rh[r] = CH[(g + 1) * 1024 + tid + r * 256];
                rl[r] = CL[(g + 1) * 1024 + tid + r * 256];
            }
        }
#pragma unroll
        for (int cc = 0; cc < 8; ++cc) {
            const int c = g * 8 + cc;
            short8 ch0 = sh_hi[buf][(cc * 2 + 0) * 64 + lane];
            short8 ch1 = sh_hi[buf][(cc * 2 + 1) * 64 + lane];
            short8 cl0 = sh_lo[buf][(cc * 2 + 0) * 64 + lane];
            short8 cl1 = sh_lo[buf][(cc * 2 + 1) * 64 + lane];
            const int cbase = c * 16 + koff;
            const f32x4 bn = *(const f32x4*)&bn_lds[cbase];
#pragma unroll
            for (int tt = 0; tt < 2; ++tt) {
                f32x4 acc = bn;
                acc = __builtin_amdgcn_mfma_f32_16x16x32_bf16(ch0, zhi[tt][0], acc, 0, 0, 0);
                acc = __builtin_amdgcn_mfma_f32_16x16x32_bf16(cl0, zhi[tt][0], acc, 0, 0, 0);
                acc = __builtin_amdgcn_mfma_f32_16x16x32_bf16(ch0, zlo[tt][0], acc, 0, 0, 0);
                acc = __builtin_amdgcn_mfma_f32_16x16x32_bf16(ch1, zhi[tt][1], acc, 0, 0, 0);
                acc = __builtin_amdgcn_mfma_f32_16x16x32_bf16(cl1, zhi[tt][1], acc, 0, 0, 0);
                acc = __builtin_amdgcn_mfma_f32_16x16x32_bf16(ch1, zlo[tt][1], acc, 0, 0, 0);
#pragma unroll
                for (int i = 0; i < 4; ++i) {
                    float u = acc[i];
                    float om1 = m1[tt];
                    bool lt = u < om1;
                    float fm = fminf(m2[tt], u);
                    m2[tt] = lt ? om1 : fm;
                    m1[tt] = lt ? u : om1;
                    bi[tt] = lt ? (cbase + i) : bi[tt];
                }
            }
        }
        // write next group into the other buffer; barrier publishes it
        if (g < 7) {
#pragma unroll
            for (int r = 0; r < 4; ++r) {
                sh_hi[buf ^ 1][tid + r * 256] = rh[r];
                sh_lo[buf ^ 1][tid + r * 256] = rl[r];
            }
            __syncthreads();
        }
    }

    // in-wave quad merge (lanes l, l^16, l^32, l^48 share a token column);
    // wave covers all codes -> result is final per token
#pragma unroll
    for (int tt = 0; tt < 2; ++tt) {
        float a1 = m1[tt], a2 = m2[tt];
        int ai = bi[tt];
        {
            float o1 = __shfl_xor(a1, 16); float o2 = __shfl_xor(a2, 16);
            int oi = __shfl_xor(ai, 16);
            top2_merge(a1, a2, ai, o1, o2, oi);
        }
        {
            float o1 = __shfl_xor(a1, 32); float o2 = __shfl_xor(a2, 32);
            int oi = __shfl_xor(ai, 32);
            top2_merge(a1, a2, ai, o1, o2, oi);
        }
        if (quad == 0) {
            const int slot = w * 32 + tt * 16 + col;
            int fl = (a2 - a1) < MARGIN;
            if (fl) {
                unsigned int pos = atomicAdd(flag_count, 1u);
                if (pos >= flag_cap) fl = 0;
                else {
                    flag_list[pos] = t0 + slot;
                    packed_min[pos] = ~0ull;   // lazy init (no memset node)
                }
            }
            s_best[slot] = ai;
            s_flag[slot] = fl;
        }
    }
    __syncthreads();

    // epilogue: 2 threads per token, 32 floats each (r6-verified); flagged deferred
    const int et = tid >> 1, h = tid & 1;
    float loss_t = 0.0f;
    if (!s_flag[et]) {
        const int B = s_best[et];
        const float4* cq  = (const float4*)(cb + (size_t)B * DIM + h * 32);
        const float4* zq4 = (const float4*)(z + (size_t)(t0 + et) * DIM + h * 32);
        float4* o4 = (float4*)(out + (size_t)(t0 + et) * DIM + h * 32);
#pragma unroll
        for (int jj = 0; jj < 8; ++jj) {
#pragma clang fp contract(off)
            float4 cc = cq[jj];
            float4 zz = zq4[jj];
            float d0 = cc.x - zz.x, d1 = cc.y - zz.y;
            float d2 = cc.z - zz.z, d3 = cc.w - zz.w;
            float4 o;
            o.x = zz.x + d0; o.y = zz.y + d1;
            o.z = zz.z + d2; o.w = zz.w + d3;
            o4[jj] = o;
            loss_t = __fmaf_rn(d0, d0, loss_t);
            loss_t = __fmaf_rn(d1, d1, loss_t);
            loss_t = __fmaf_rn(d2, d2, loss_t);
            loss_t = __fmaf_rn(d3, d3, loss_t);
        }
        if (h == 0) out[OUT_IDX_OFF + t0 + et] = (float)B;
    }
#pragma unroll
    for (int off = 32; off > 0; off >>= 1)
        loss_t += __shfl_down(loss_t, off);
    if (lane == 0) atomicAdd(loss_sum, (double)loss_t);
}

__device__ __forceinline__ unsigned long long shfl_down_u64(unsigned long long v, int off) {
    unsigned int lo = (unsigned int)v, hi = (unsigned int)(v >> 32);
    lo = __shfl_down(lo, off);
    hi = __shfl_down(hi, off);
    return ((unsigned long long)hi << 32) | lo;
}

// ---------------------------------------------------------------------------
// Exact numpy-bitwise pass (code-stationary) — verified absmax=0 rounds 6-8.
// ---------------------------------------------------------------------------
__global__ __launch_bounds__(256) void vq_exact_min(
    const float* __restrict__ z, const float* __restrict__ cb,
    const float* __restrict__ bnorm,
    const unsigned int* __restrict__ flag_count,
    const int* __restrict__ flag_list,
    unsigned long long* __restrict__ packed_min, unsigned int flag_cap) {
    __shared__ float zsh[64 * 68];
    __shared__ float szs[64];

    const int tid = threadIdx.x;
    const int w = tid >> 6;
    const int lane = tid & 63;
    unsigned int count = *flag_count;
    if (count > flag_cap) count = flag_cap;
    const unsigned int ngroups = (count + 63) >> 6;

    const int q = blockIdx.x & 3;
    const unsigned int g = blockIdx.x >> 2;          // 0..127; ngroups <= 128
    if (g >= ngroups) return;

    const int k = q * 256 + w * 64 + lane;           // this lane's code

    float row[DIM];
    {
        const float4* c4 = (const float4*)(cb + (size_t)k * DIM);
#pragma unroll
        for (int j = 0; j < 16; ++j) {
            float4 v = c4[j];
            row[4 * j + 0] = v.x; row[4 * j + 1] = v.y;
            row[4 * j + 2] = v.z; row[4 * j + 3] = v.w;
        }
    }
    const float bnk = bnorm[k];

    {
        const int i = tid >> 2, part = tid & 3;
        const unsigned int li = g * 64 + i;
        if (li < count) {
            const int t = flag_list[li];
            const float4* zp = (const float4*)(z + (size_t)t * DIM + part * 16);
            float4* dst = (float4*)(zsh + i * 68 + part * 16);
#pragma unroll
            for (int e = 0; e < 4; ++e) dst[e] = zp[e];
        }
    }
    __syncthreads();
    if (tid < 64) szs[tid] = np_sumsq64(zsh + tid * 68);
    __syncthreads();

    for (int tt = 0; tt < 64; ++tt) {
        const unsigned int li = g * 64 + tt;
        const float* zp = zsh + tt * 68;             // wave-uniform -> broadcast
        float l16[16];
#pragma unroll
        for (int g2 = 0; g2 < 4; ++g2) {
            float4 v0 = ((const float4*)(zp + 4 * g2))[0];
            float4 v1 = ((const float4*)(zp + 16 + 4 * g2))[0];
            float4 v2 = ((const float4*)(zp + 32 + 4 * g2))[0];
            float4 v3 = ((const float4*)(zp + 48 + 4 * g2))[0];
            float a0[4] = {v0.x, v0.y, v0.z, v0.w};
            float a1[4] = {v1.x, v1.y, v1.z, v1.w};
            float a2[4] = {v2.x, v2.y, v2.z, v2.w};
            float a3[4] = {v3.x, v3.y, v3.z, v3.w};
#pragma unroll
            for (int e = 0; e < 4; ++e) {
#pragma clang fp contract(off)
                int jj = 4 * g2 + e;
                float acc = a3[e] * row[48 + jj];
                acc = __fmaf_rn(a2[e], row[32 + jj], acc);
                acc = __fmaf_rn(a1[e], row[16 + jj], acc);
                acc = __fmaf_rn(a0[e], row[jj],      acc);
                l16[jj] = acc;
            }
        }
        float e_np;
        {
#pragma clang fp contract(off)
#pragma unroll
            for (int jj = 0; jj < 8; ++jj) l16[jj] = l16[jj] + l16[jj + 8];
#pragma unroll
            for (int jj = 0; jj < 4; ++jj) l16[jj] = l16[jj] + l16[jj + 4];
            l16[0] = l16[0] + l16[2];
            l16[1] = l16[1] + l16[3];
            e_np = l16[0] + l16[1];
        }
        float dd;
        {
#pragma clang fp contract(off)
            float t1 = szs[tt] + bnk;
            float mm = 2.0f * e_np;
            dd = t1 - mm;
        }
        unsigned long long pk =
            ((unsigned long long)__float_as_uint(dd) << 10) | (unsigned int)k;
#pragma unroll
        for (int off = 32; off > 0; off >>= 1) {
            unsigned long long o = shfl_down_u64(pk, off);
            pk = (o < pk) ? o : pk;
        }
        if (lane == 0 && li < count)
            atomicMin(&packed_min[li], pk);
    }
}

// flagged-token outputs + fused final loss write (done-counter; last block)
__global__ __launch_bounds__(256) void vq_finish(
    const float* __restrict__ z, const float* __restrict__ cb,
    float* __restrict__ out, const unsigned int* __restrict__ flag_count,
    const int* __restrict__ flag_list,
    const unsigned long long* __restrict__ packed_min,
    double* __restrict__ loss_sum, unsigned int* __restrict__ done,
    unsigned int flag_cap) {
    const int lane = threadIdx.x & 63;
    unsigned int count = *flag_count;
    if (count > flag_cap) count = flag_cap;
    const unsigned int gw = blockIdx.x * 4 + (threadIdx.x >> 6);
    const unsigned int NW = gridDim.x * 4;

    for (unsigned int li = gw; li < count; li += NW) {
        const int t = flag_list[li];
        const int best = (int)(packed_min[li] & 1023ull);
        const float zl = z[(size_t)t * DIM + lane];
        const float zq = cb[(size_t)best * DIM + lane];
        float d, o;
        {
#pragma clang fp contract(off)
            d = zq - zl;
            o = zl + d;
        }
        out[(size_t)t * DIM + lane] = o;
        float l2 = d * d;
#pragma unroll
        for (int off = 32; off > 0; off >>= 1)
            l2 += __shfl_down(l2, off);
        if (lane == 0) {
            out[OUT_IDX_OFF + t] = (float)best;
            atomicAdd(loss_sum, (double)l2);
        }
    }

    __threadfence();
    __syncthreads();
    if (threadIdx.x == 0) {
        unsigned int old = atomicAdd(done, 1u);
        if (old == gridDim.x - 1) {
            double L = atomicAdd(loss_sum, 0.0);   // coherent read-through
            out[OUT_LOSS_OFF] = (float)(2.0 * L / (double)((size_t)TOKENS * DIM));
        }
    }
}

extern "C" void kernel_launch(void* const* d_in, const int* in_sizes, int n_in,
                              void* d_out, int out_size, void* d_ws, size_t ws_size,
                              hipStream_t stream) {
    const float* z  = (const float*)d_in[0];   // [8,8192,64] f32
    const float* cb = (const float*)d_in[1];   // [1024,64] f32
    float* out = (float*)d_out;

    char* ws = (char*)d_ws;
    double* loss_sum = (double*)(ws + WS_LOSS);
    unsigned int* flag_count = (unsigned int*)(ws + WS_FLAGC);
    unsigned int* done = (unsigned int*)(ws + WS_DONE);
    float* bnorm = (float*)(ws + WS_BNORM);
    unsigned short* chi = (unsigned short*)(ws + WS_CHI);
    unsigned short* clo = (unsigned short*)(ws + WS_CLO);
    unsigned long long* packed = (unsigned long long*)(ws + WS_PACKED);
    int* flag_list = (int*)(ws + WS_FLAGS);

    unsigned int cap = 0;
    if (ws_size > WS_FLAGS + 4) {
        size_t c = (ws_size - WS_FLAGS) / 4;
        cap = (c > FLAG_CAP) ? FLAG_CAP : (unsigned int)c;
    }

    vq_prep<<<dim3(256), dim3(256), 0, stream>>>(
        cb, chi, clo, bnorm, loss_sum, flag_count, done);
    vq_fast<<<dim3(TOKENS / 128), dim3(256), 0, stream>>>(
        z, cb, chi, clo, bnorm, out, flag_count, flag_list, packed, loss_sum, cap);
    vq_exact_min<<<dim3(512), dim3(256), 0, stream>>>(
        z, cb, bnorm, flag_count, flag_list, packed, cap);
    vq_finish<<<dim3(128), dim3(256), 0, stream>>>(
        z, cb, out, flag_count, flag_list, packed, loss_sum, done, cap);
}

// Round 10
// 189.341 us; speedup vs baseline: 1.4449x; 1.3819x over previous
//
#include <hip/hip_runtime.h>

#define TOKENS 65536
#define DIM 64
#define NCODE 1024
#define MARGIN 6e-5f
#define FLAG_CAP 8192

#define OUT_IDX_OFF ((size_t)TOKENS * DIM)          // 4194304
#define OUT_LOSS_OFF (OUT_IDX_OFF + TOKENS)         // 4259840

// ws layout (bytes):
#define WS_LOSS   0        // double
#define WS_FLAGC  8        // uint
#define WS_DONEA  12       // uint (global finisher counter)
#define WS_DGRP   16       // uint[128] per-group done counters -> 528
#define WS_BNORM  528      // f32[1024] -> 4624
#define WS_CHI    4624     // ushort[65536] -> 135696 (codebook -2c hi, A-frag)
#define WS_CLO    135696   // ushort[65536] -> 266768 (codebook -2c lo)
#define WS_PACKED 266768   // u64[8192] -> 332304 (per-flagged argmin)
#define WS_FLAGS  332304   // int[8192] -> 365072

typedef __attribute__((ext_vector_type(8))) short short8;
typedef __attribute__((ext_vector_type(4))) float f32x4;

// ---------------------------------------------------------------------------
// numpy-bitwise f32 sum-of-squares — VERIFIED absmax=0 (round 2). Do not touch.
// ---------------------------------------------------------------------------
__device__ __forceinline__ float np_sumsq64(const float* __restrict__ x) {
#pragma clang fp contract(off)
    float r[8];
#pragma unroll
    for (int j = 0; j < 8; ++j) r[j] = x[j] * x[j];
#pragma unroll
    for (int i = 8; i < 64; i += 8) {
#pragma unroll
        for (int j = 0; j < 8; ++j) {
            float sq = x[i + j] * x[i + j];
            r[j] = r[j] + sq;
        }
    }
    return ((r[0] + r[1]) + (r[2] + r[3])) + ((r[4] + r[5]) + (r[6] + r[7]));
}

// ---------------------------------------------------------------------------
// Prep: codebook -> bf16 hi/lo A-frags of (-2*C) + bnorm; zero-inits all
// control words (loss/flagc/done/done_grp). Verified absmax=0 rounds 4-9.
// ---------------------------------------------------------------------------
__global__ __launch_bounds__(256) void vq_prep(
    const float* __restrict__ cb, unsigned short* __restrict__ chi,
    unsigned short* __restrict__ clo, float* __restrict__ bnorm,
    unsigned int* __restrict__ ctrl /* 132 u32 at ws+0 */) {
    int tid = blockIdx.x * 256 + threadIdx.x;   // 0..65535
    if (tid < 132) ctrl[tid] = 0u;
    int j = tid & 7;
    int L = (tid >> 3) & 63;
    int cs = tid >> 9;          // 0..127
    int s = cs & 1, c = cs >> 1;
    int code = c * 16 + (L & 15);
    int d = s * 32 + (L >> 4) * 8 + j;
    float v = -2.0f * cb[(size_t)code * DIM + d];
    unsigned int b = __float_as_uint(v);
    chi[tid] = (unsigned short)(b >> 16);                       // truncation split
    float hf = __uint_as_float(b & 0xFFFF0000u);
    float lo;
    {
#pragma clang fp contract(off)
        lo = v - hf;                                            // exact in f32
    }
    clo[tid] = (unsigned short)(__float_as_uint(lo) >> 16);

    if (tid < NCODE) bnorm[tid] = np_sumsq64(cb + (size_t)tid * DIM);
}

__device__ __forceinline__ void top2_merge(float& a1, float& a2, int& ai,
                                           float b1, float b2, int bi) {
    float n1 = fminf(a1, b1);
    float n2 = fminf(fmaxf(a1, b1), fminf(a2, b2));
    ai = (b1 < a1) ? bi : ai;   // ties keep a (exact ties get flagged anyway)
    a1 = n1; a2 = n2;
}

// ---------------------------------------------------------------------------
// Fast screen, v6: LDS double buffer with 4-chunk groups (37 KB LDS -> 4
// blocks/CU, 16 waves/CU). Block = 4 waves x 32 tokens = 128 tokens; each
// wave scans ALL 1024 codes in 16 groups of 4 chunks. MFMA chain + all
// numerics identical to verified rounds 4-9. WRITE_SIZE = spill detector.
// ---------------------------------------------------------------------------
__global__ __launch_bounds__(256, 4) void vq_fast(
    const float* __restrict__ z, const float* __restrict__ cb,
    const unsigned short* __restrict__ cfrag_hi,
    const unsigned short* __restrict__ cfrag_lo,
    const float* __restrict__ bnorm, float* __restrict__ out,
    unsigned int* __restrict__ flag_count, int* __restrict__ flag_list,
    unsigned long long* __restrict__ packed_min,
    double* __restrict__ loss_sum, unsigned int flag_cap) {
    __shared__ short8 sh_hi[2][512];   // [buf][(cc*2+step)*64 + lane], 8KB each
    __shared__ short8 sh_lo[2][512];
    __shared__ float bn_lds[NCODE];
    __shared__ int s_best[128];
    __shared__ int s_flag[128];

    const int tid = threadIdx.x;
    const int lane = tid & 63;
    const int w = tid >> 6;
    const int t0 = blockIdx.x * 128;
    const int tw = t0 + w * 32;              // this wave's 32 tokens
    const int col = lane & 15;
    const int quad = lane >> 4;

    // stage bnorm into LDS (4 KB)
    ((float4*)bn_lds)[tid] = ((const float4*)bnorm)[tid];

    // token B-fragments (bf16 hi/lo), 2 tiles x 2 K-steps, in registers
    short8 zhi[2][2], zlo[2][2];
#pragma unroll
    for (int tt = 0; tt < 2; ++tt) {
#pragma unroll
        for (int s = 0; s < 2; ++s) {
            const float* zp = z + (size_t)(tw + tt * 16 + col) * DIM + s * 32 + quad * 8;
            float4 f0 = ((const float4*)zp)[0];
            float4 f1 = ((const float4*)zp)[1];
            float f[8] = {f0.x, f0.y, f0.z, f0.w, f1.x, f1.y, f1.z, f1.w};
            short8 h, l;
#pragma unroll
            for (int j = 0; j < 8; ++j) {
                unsigned int b = __float_as_uint(f[j]);
                h[j] = (short)(b >> 16);
                float hf = __uint_as_float(b & 0xFFFF0000u);
                float lo;
                {
#pragma clang fp contract(off)
                    lo = f[j] - hf;
                }
                l[j] = (short)(__float_as_uint(lo) >> 16);
            }
            zhi[tt][s] = h; zlo[tt][s] = l;
        }
    }

    const short8* CH = (const short8*)cfrag_hi;   // 4096 short8 (64 chunks)
    const short8* CL = (const short8*)cfrag_lo;

    // stage group 0 (4 chunks = 512 short8 per array; 2 per thread per array)
    {
        short8 a0 = CH[tid], a1 = CH[tid + 256];
        short8 b0 = CL[tid], b1 = CL[tid + 256];
        sh_hi[0][tid] = a0; sh_hi[0][tid + 256] = a1;
        sh_lo[0][tid] = b0; sh_lo[0][tid + 256] = b1;
    }
    __syncthreads();

    float m1[2] = {3.0e38f, 3.0e38f};
    float m2[2] = {3.0e38f, 3.0e38f};
    int bi[2] = {0, 0};
    const int koff = quad * 4;

    for (int g = 0; g < 16; ++g) {
        const int buf = g & 1;
        short8 a0, a1, b0, b1;
        if (g < 15) {               // issue next group's loads first
            const int base = (g + 1) * 512 + tid;
            a0 = CH[base]; a1 = CH[base + 256];
            b0 = CL[base]; b1 = CL[base + 256];
        }
#pragma unroll
        for (int cc = 0; cc < 4; ++cc) {
            const int c = g * 4 + cc;
            short8 ch0 = sh_hi[buf][(cc * 2 + 0) * 64 + lane];
            short8 ch1 = sh_hi[buf][(cc * 2 + 1) * 64 + lane];
            short8 cl0 = sh_lo[buf][(cc * 2 + 0) * 64 + lane];
            short8 cl1 = sh_lo[buf][(cc * 2 + 1) * 64 + lane];
            const int cbase = c * 16 + koff;
            const f32x4 bn = *(const f32x4*)&bn_lds[cbase];
#pragma unroll
            for (int tt = 0; tt < 2; ++tt) {
                f32x4 acc = bn;
                acc = __builtin_amdgcn_mfma_f32_16x16x32_bf16(ch0, zhi[tt][0], acc, 0, 0, 0);
                acc = __builtin_amdgcn_mfma_f32_16x16x32_bf16(cl0, zhi[tt][0], acc, 0, 0, 0);
                acc = __builtin_amdgcn_mfma_f32_16x16x32_bf16(ch0, zlo[tt][0], acc, 0, 0, 0);
                acc = __builtin_amdgcn_mfma_f32_16x16x32_bf16(ch1, zhi[tt][1], acc, 0, 0, 0);
                acc = __builtin_amdgcn_mfma_f32_16x16x32_bf16(cl1, zhi[tt][1], acc, 0, 0, 0);
                acc = __builtin_amdgcn_mfma_f32_16x16x32_bf16(ch1, zlo[tt][1], acc, 0, 0, 0);
#pragma unroll
                for (int i = 0; i < 4; ++i) {
                    float u = acc[i];
                    float om1 = m1[tt];
                    bool lt = u < om1;
                    float fm = fminf(m2[tt], u);
                    m2[tt] = lt ? om1 : fm;
                    m1[tt] = lt ? u : om1;
                    bi[tt] = lt ? (cbase + i) : bi[tt];
                }
            }
        }
        if (g < 15) {
            sh_hi[buf ^ 1][tid] = a0; sh_hi[buf ^ 1][tid + 256] = a1;
            sh_lo[buf ^ 1][tid] = b0; sh_lo[buf ^ 1][tid + 256] = b1;
            __syncthreads();
        }
    }

    // in-wave quad merge (lanes l, l^16, l^32, l^48 share a token column)
#pragma unroll
    for (int tt = 0; tt < 2; ++tt) {
        float a1 = m1[tt], a2 = m2[tt];
        int ai = bi[tt];
        {
            float o1 = __shfl_xor(a1, 16); float o2 = __shfl_xor(a2, 16);
            int oi = __shfl_xor(ai, 16);
            top2_merge(a1, a2, ai, o1, o2, oi);
        }
        {
            float o1 = __shfl_xor(a1, 32); float o2 = __shfl_xor(a2, 32);
            int oi = __shfl_xor(ai, 32);
            top2_merge(a1, a2, ai, o1, o2, oi);
        }
        if (quad == 0) {
            const int slot = w * 32 + tt * 16 + col;
            int fl = (a2 - a1) < MARGIN;
            if (fl) {
                unsigned int pos = atomicAdd(flag_count, 1u);
                if (pos >= flag_cap) fl = 0;
                else {
                    flag_list[pos] = t0 + slot;
                    packed_min[pos] = ~0ull;   // lazy init (no memset node)
                }
            }
            s_best[slot] = ai;
            s_flag[slot] = fl;
        }
    }
    __syncthreads();

    // epilogue: 2 threads per token, 32 floats each (r6-verified); flagged deferred
    const int et = tid >> 1, h = tid & 1;
    float loss_t = 0.0f;
    if (!s_flag[et]) {
        const int B = s_best[et];
        const float4* cq  = (const float4*)(cb + (size_t)B * DIM + h * 32);
        const float4* zq4 = (const float4*)(z + (size_t)(t0 + et) * DIM + h * 32);
        float4* o4 = (float4*)(out + (size_t)(t0 + et) * DIM + h * 32);
#pragma unroll
        for (int jj = 0; jj < 8; ++jj) {
#pragma clang fp contract(off)
            float4 cc = cq[jj];
            float4 zz = zq4[jj];
            float d0 = cc.x - zz.x, d1 = cc.y - zz.y;
            float d2 = cc.z - zz.z, d3 = cc.w - zz.w;
            float4 o;
            o.x = zz.x + d0; o.y = zz.y + d1;
            o.z = zz.z + d2; o.w = zz.w + d3;
            o4[jj] = o;
            loss_t = __fmaf_rn(d0, d0, loss_t);
            loss_t = __fmaf_rn(d1, d1, loss_t);
            loss_t = __fmaf_rn(d2, d2, loss_t);
            loss_t = __fmaf_rn(d3, d3, loss_t);
        }
        if (h == 0) out[OUT_IDX_OFF + t0 + et] = (float)B;
    }
#pragma unroll
    for (int off = 32; off > 0; off >>= 1)
        loss_t += __shfl_down(loss_t, off);
    if (lane == 0) atomicAdd(loss_sum, (double)loss_t);
}

__device__ __forceinline__ unsigned long long shfl_down_u64(unsigned long long v, int off) {
    unsigned int lo = (unsigned int)v, hi = (unsigned int)(v >> 32);
    lo = __shfl_down(lo, off);
    hi = __shfl_down(hi, off);
    return ((unsigned long long)hi << 32) | lo;
}

// ---------------------------------------------------------------------------
// Exact numpy-bitwise pass (code-stationary, verified rounds 6-9) with the
// finish phase FUSED: 4 quarter-blocks per token-group; the 4th to finish
// (per-group done counter) writes that group's outputs; the last finisher
// writes the loss. Coherent cross-XCD reads via atomicAdd(p,0).
// ---------------------------------------------------------------------------
__global__ __launch_bounds__(256) void vq_exact_min(
    const float* __restrict__ z, const float* __restrict__ cb,
    const float* __restrict__ bnorm,
    const unsigned int* __restrict__ flag_count,
    const int* __restrict__ flag_list,
    unsigned long long* __restrict__ packed_min,
    unsigned int* __restrict__ done_grp, unsigned int* __restrict__ done_all,
    float* __restrict__ out, double* __restrict__ loss_sum,
    unsigned int flag_cap) {
    __shared__ float zsh[64 * 68];
    __shared__ float szs[64];
    __shared__ unsigned int s_old;

    const int tid = threadIdx.x;
    const int w = tid >> 6;
    const int lane = tid & 63;
    unsigned int count = *flag_count;
    if (count > flag_cap) count = flag_cap;
    const unsigned int ngroups = (count + 63) >> 6;

    if (count == 0) {   // no flagged tokens: block 0 writes the loss
        if (blockIdx.x == 0 && tid == 0) {
            double L = atomicAdd(loss_sum, 0.0);
            out[OUT_LOSS_OFF] = (float)(2.0 * L / (double)((size_t)TOKENS * DIM));
        }
        return;
    }

    const int q = blockIdx.x & 3;
    const unsigned int g = blockIdx.x >> 2;          // 0..127; ngroups <= 128
    if (g >= ngroups) return;

    const int k = q * 256 + w * 64 + lane;           // this lane's code

    float row[DIM];
    {
        const float4* c4 = (const float4*)(cb + (size_t)k * DIM);
#pragma unroll
        for (int j = 0; j < 16; ++j) {
            float4 v = c4[j];
            row[4 * j + 0] = v.x; row[4 * j + 1] = v.y;
            row[4 * j + 2] = v.z; row[4 * j + 3] = v.w;
        }
    }
    const float bnk = bnorm[k];

    {
        const int i = tid >> 2, part = tid & 3;
        const unsigned int li = g * 64 + i;
        if (li < count) {
            const int t = flag_list[li];
            const float4* zp = (const float4*)(z + (size_t)t * DIM + part * 16);
            float4* dst = (float4*)(zsh + i * 68 + part * 16);
#pragma unroll
            for (int e = 0; e < 4; ++e) dst[e] = zp[e];
        }
    }
    __syncthreads();
    if (tid < 64) szs[tid] = np_sumsq64(zsh + tid * 68);
    __syncthreads();

    for (int tt = 0; tt < 64; ++tt) {
        const unsigned int li = g * 64 + tt;
        const float* zp = zsh + tt * 68;             // wave-uniform -> broadcast
        float l16[16];
#pragma unroll
        for (int g2 = 0; g2 < 4; ++g2) {
            float4 v0 = ((const float4*)(zp + 4 * g2))[0];
            float4 v1 = ((const float4*)(zp + 16 + 4 * g2))[0];
            float4 v2 = ((const float4*)(zp + 32 + 4 * g2))[0];
            float4 v3 = ((const float4*)(zp + 48 + 4 * g2))[0];
            float a0[4] = {v0.x, v0.y, v0.z, v0.w};
            float a1[4] = {v1.x, v1.y, v1.z, v1.w};
            float a2[4] = {v2.x, v2.y, v2.z, v2.w};
            float a3[4] = {v3.x, v3.y, v3.z, v3.w};
#pragma unroll
            for (int e = 0; e < 4; ++e) {
#pragma clang fp contract(off)
                int jj = 4 * g2 + e;
                float acc = a3[e] * row[48 + jj];
                acc = __fmaf_rn(a2[e], row[32 + jj], acc);
                acc = __fmaf_rn(a1[e], row[16 + jj], acc);
                acc = __fmaf_rn(a0[e], row[jj],      acc);
                l16[jj] = acc;
            }
        }
        float e_np;
        {
#pragma clang fp contract(off)
#pragma unroll
            for (int jj = 0; jj < 8; ++jj) l16[jj] = l16[jj] + l16[jj + 8];
#pragma unroll
            for (int jj = 0; jj < 4; ++jj) l16[jj] = l16[jj] + l16[jj + 4];
            l16[0] = l16[0] + l16[2];
            l16[1] = l16[1] + l16[3];
            e_np = l16[0] + l16[1];
        }
        float dd;
        {
#pragma clang fp contract(off)
            float t1 = szs[tt] + bnk;
            float mm = 2.0f * e_np;
            dd = t1 - mm;
        }
        unsigned long long pk =
            ((unsigned long long)__float_as_uint(dd) << 10) | (unsigned int)k;
#pragma unroll
        for (int off = 32; off > 0; off >>= 1) {
            unsigned long long o = shfl_down_u64(pk, off);
            pk = (o < pk) ? o : pk;
        }
        if (lane == 0 && li < count)
            atomicMin(&packed_min[li], pk);
    }

    // ---- fused finish: 4th quarter-block of this group writes outputs ----
    __threadfence();
    __syncthreads();
    if (tid == 0) s_old = atomicAdd(&done_grp[g], 1u);
    __syncthreads();
    if (s_old != 3u) return;
    __threadfence();

    for (int tt = w * 16; tt < w * 16 + 16; ++tt) {
        const unsigned int li = g * 64 + tt;
        if (li >= count) break;
        const int t = flag_list[li];
        const unsigned long long pk = atomicAdd(&packed_min[li], 0ull);  // coherent
        const int best = (int)(pk & 1023ull);
        const float zl = zsh[tt * 68 + lane];
        const float zq = cb[(size_t)best * DIM + lane];
        float d, o;
        {
#pragma clang fp contract(off)
            d = zq - zl;
            o = zl + d;
        }
        out[(size_t)t * DIM + lane] = o;
        float l2 = d * d;
#pragma unroll
        for (int off = 32; off > 0; off >>= 1)
            l2 += __shfl_down(l2, off);
        if (lane == 0) {
            out[OUT_IDX_OFF + t] = (float)best;
            atomicAdd(loss_sum, (double)l2);
        }
    }

    __threadfence();
    __syncthreads();
    if (tid == 0) {
        unsigned int old = atomicAdd(done_all, 1u);
        if (old == ngroups - 1) {
            double L = atomicAdd(loss_sum, 0.0);   // coherent read-through
            out[OUT_LOSS_OFF] = (float)(2.0 * L / (double)((size_t)TOKENS * DIM));
        }
    }
}

extern "C" void kernel_launch(void* const* d_in, const int* in_sizes, int n_in,
                              void* d_out, int out_size, void* d_ws, size_t ws_size,
                              hipStream_t stream) {
    const float* z  = (const float*)d_in[0];   // [8,8192,64] f32
    const float* cb = (const float*)d_in[1];   // [1024,64] f32
    float* out = (float*)d_out;

    char* ws = (char*)d_ws;
    double* loss_sum = (double*)(ws + WS_LOSS);
    unsigned int* flag_count = (unsigned int*)(ws + WS_FLAGC);
    unsigned int* done_all = (unsigned int*)(ws + WS_DONEA);
    unsigned int* done_grp = (unsigned int*)(ws + WS_DGRP);
    float* bnorm = (float*)(ws + WS_BNORM);
    unsigned short* chi = (unsigned short*)(ws + WS_CHI);
    unsigned short* clo = (unsigned short*)(ws + WS_CLO);
    unsigned long long* packed = (unsigned long long*)(ws + WS_PACKED);
    int* flag_list = (int*)(ws + WS_FLAGS);

    unsigned int cap = 0;
    if (ws_size > WS_FLAGS + 4) {
        size_t c = (ws_size - WS_FLAGS) / 4;
        cap = (c > FLAG_CAP) ? FLAG_CAP : (unsigned int)c;
    }

    vq_prep<<<dim3(256), dim3(256), 0, stream>>>(
        cb, chi, clo, bnorm, (unsigned int*)ws);
    vq_fast<<<dim3(TOKENS / 128), dim3(256), 0, stream>>>(
        z, cb, chi, clo, bnorm, out, flag_count, flag_list, packed, loss_sum, cap);
    vq_exact_min<<<dim3(512), dim3(256), 0, stream>>>(
        z, cb, bnorm, flag_count, flag_list, packed, done_grp, done_all,
        out, loss_sum, cap);
}

// Round 11
// 169.676 us; speedup vs baseline: 1.6123x; 1.1159x over previous
//
#include <hip/hip_runtime.h>

#define TOKENS 65536
#define DIM 64
#define NCODE 1024
#define MARGIN 6e-5f
#define FLAG_CAP 8192
#define TPG 16   // tokens per exact-pass group (r10: 64 -> serialization bound)

#define OUT_IDX_OFF ((size_t)TOKENS * DIM)          // 4194304
#define OUT_LOSS_OFF (OUT_IDX_OFF + TOKENS)         // 4259840

// ws layout (bytes):
#define WS_LOSS   0        // double
#define WS_FLAGC  8        // uint
#define WS_DONEA  12       // uint (global finisher counter)
#define WS_DGRP   16       // uint[512] per-group done counters -> 2064
#define WS_BNORM  2064     // f32[1024] -> 6160
#define WS_CHI    6160     // ushort[65536] -> 137232 (codebook -2c hi, A-frag)
#define WS_CLO    137232   // ushort[65536] -> 268304 (codebook -2c lo)
#define WS_PACKED 268304   // u64[8192] -> 333840 (per-flagged argmin)
#define WS_FLAGS  333840   // int[8192] -> 366608

typedef __attribute__((ext_vector_type(8))) short short8;
typedef __attribute__((ext_vector_type(4))) float f32x4;

// ---------------------------------------------------------------------------
// numpy-bitwise f32 sum-of-squares — VERIFIED absmax=0 (round 2). Do not touch.
// ---------------------------------------------------------------------------
__device__ __forceinline__ float np_sumsq64(const float* __restrict__ x) {
#pragma clang fp contract(off)
    float r[8];
#pragma unroll
    for (int j = 0; j < 8; ++j) r[j] = x[j] * x[j];
#pragma unroll
    for (int i = 8; i < 64; i += 8) {
#pragma unroll
        for (int j = 0; j < 8; ++j) {
            float sq = x[i + j] * x[i + j];
            r[j] = r[j] + sq;
        }
    }
    return ((r[0] + r[1]) + (r[2] + r[3])) + ((r[4] + r[5]) + (r[6] + r[7]));
}

// ---------------------------------------------------------------------------
// Prep: codebook -> bf16 hi/lo A-frags of (-2*C) + bnorm; zero-inits all 516
// control words (loss/flagc/done_all/done_grp[512]). Verified rounds 4-10.
// ---------------------------------------------------------------------------
__global__ __launch_bounds__(256) void vq_prep(
    const float* __restrict__ cb, unsigned short* __restrict__ chi,
    unsigned short* __restrict__ clo, float* __restrict__ bnorm,
    unsigned int* __restrict__ ctrl /* 516 u32 at ws+0 */) {
    int tid = blockIdx.x * 256 + threadIdx.x;   // 0..65535
    if (tid < 516) ctrl[tid] = 0u;
    int j = tid & 7;
    int L = (tid >> 3) & 63;
    int cs = tid >> 9;          // 0..127
    int s = cs & 1, c = cs >> 1;
    int code = c * 16 + (L & 15);
    int d = s * 32 + (L >> 4) * 8 + j;
    float v = -2.0f * cb[(size_t)code * DIM + d];
    unsigned int b = __float_as_uint(v);
    chi[tid] = (unsigned short)(b >> 16);                       // truncation split
    float hf = __uint_as_float(b & 0xFFFF0000u);
    float lo;
    {
#pragma clang fp contract(off)
        lo = v - hf;                                            // exact in f32
    }
    clo[tid] = (unsigned short)(__float_as_uint(lo) >> 16);

    if (tid < NCODE) bnorm[tid] = np_sumsq64(cb + (size_t)tid * DIM);
}

__device__ __forceinline__ void top2_merge(float& a1, float& a2, int& ai,
                                           float b1, float b2, int bi) {
    float n1 = fminf(a1, b1);
    float n2 = fminf(fmaxf(a1, b1), fminf(a2, b2));
    ai = (b1 < a1) ? bi : ai;   // ties keep a (exact ties get flagged anyway)
    a1 = n1; a2 = n2;
}

// ---------------------------------------------------------------------------
// Fast screen, v6 (UNCHANGED from r10 to isolate this round's variable).
// LDS double buffer, 4-chunk groups, 4 blocks/CU. Block = 4 waves x 32
// tokens; each wave scans all 1024 codes. Numerics verified rounds 4-10.
// ---------------------------------------------------------------------------
__global__ __launch_bounds__(256, 4) void vq_fast(
    const float* __restrict__ z, const float* __restrict__ cb,
    const unsigned short* __restrict__ cfrag_hi,
    const unsigned short* __restrict__ cfrag_lo,
    const float* __restrict__ bnorm, float* __restrict__ out,
    unsigned int* __restrict__ flag_count, int* __restrict__ flag_list,
    unsigned long long* __restrict__ packed_min,
    double* __restrict__ loss_sum, unsigned int flag_cap) {
    __shared__ short8 sh_hi[2][512];   // [buf][(cc*2+step)*64 + lane], 8KB each
    __shared__ short8 sh_lo[2][512];
    __shared__ float bn_lds[NCODE];
    __shared__ int s_best[128];
    __shared__ int s_flag[128];

    const int tid = threadIdx.x;
    const int lane = tid & 63;
    const int w = tid >> 6;
    const int t0 = blockIdx.x * 128;
    const int tw = t0 + w * 32;              // this wave's 32 tokens
    const int col = lane & 15;
    const int quad = lane >> 4;

    // stage bnorm into LDS (4 KB)
    ((float4*)bn_lds)[tid] = ((const float4*)bnorm)[tid];

    // token B-fragments (bf16 hi/lo), 2 tiles x 2 K-steps, in registers
    short8 zhi[2][2], zlo[2][2];
#pragma unroll
    for (int tt = 0; tt < 2; ++tt) {
#pragma unroll
        for (int s = 0; s < 2; ++s) {
            const float* zp = z + (size_t)(tw + tt * 16 + col) * DIM + s * 32 + quad * 8;
            float4 f0 = ((const float4*)zp)[0];
            float4 f1 = ((const float4*)zp)[1];
            float f[8] = {f0.x, f0.y, f0.z, f0.w, f1.x, f1.y, f1.z, f1.w};
            short8 h, l;
#pragma unroll
            for (int j = 0; j < 8; ++j) {
                unsigned int b = __float_as_uint(f[j]);
                h[j] = (short)(b >> 16);
                float hf = __uint_as_float(b & 0xFFFF0000u);
                float lo;
                {
#pragma clang fp contract(off)
                    lo = f[j] - hf;
                }
                l[j] = (short)(__float_as_uint(lo) >> 16);
            }
            zhi[tt][s] = h; zlo[tt][s] = l;
        }
    }

    const short8* CH = (const short8*)cfrag_hi;   // 4096 short8 (64 chunks)
    const short8* CL = (const short8*)cfrag_lo;

    // stage group 0 (4 chunks = 512 short8 per array; 2 per thread per array)
    {
        short8 a0 = CH[tid], a1 = CH[tid + 256];
        short8 b0 = CL[tid], b1 = CL[tid + 256];
        sh_hi[0][tid] = a0; sh_hi[0][tid + 256] = a1;
        sh_lo[0][tid] = b0; sh_lo[0][tid + 256] = b1;
    }
    __syncthreads();

    float m1[2] = {3.0e38f, 3.0e38f};
    float m2[2] = {3.0e38f, 3.0e38f};
    int bi[2] = {0, 0};
    const int koff = quad * 4;

    for (int g = 0; g < 16; ++g) {
        const int buf = g & 1;
        short8 a0, a1, b0, b1;
        if (g < 15) {               // issue next group's loads first
            const int base = (g + 1) * 512 + tid;
            a0 = CH[base]; a1 = CH[base + 256];
            b0 = CL[base]; b1 = CL[base + 256];
        }
#pragma unroll
        for (int cc = 0; cc < 4; ++cc) {
            const int c = g * 4 + cc;
            short8 ch0 = sh_hi[buf][(cc * 2 + 0) * 64 + lane];
            short8 ch1 = sh_hi[buf][(cc * 2 + 1) * 64 + lane];
            short8 cl0 = sh_lo[buf][(cc * 2 + 0) * 64 + lane];
            short8 cl1 = sh_lo[buf][(cc * 2 + 1) * 64 + lane];
            const int cbase = c * 16 + koff;
            const f32x4 bn = *(const f32x4*)&bn_lds[cbase];
#pragma unroll
            for (int tt = 0; tt < 2; ++tt) {
                f32x4 acc = bn;
                acc = __builtin_amdgcn_mfma_f32_16x16x32_bf16(ch0, zhi[tt][0], acc, 0, 0, 0);
                acc = __builtin_amdgcn_mfma_f32_16x16x32_bf16(cl0, zhi[tt][0], acc, 0, 0, 0);
                acc = __builtin_amdgcn_mfma_f32_16x16x32_bf16(ch0, zlo[tt][0], acc, 0, 0, 0);
                acc = __builtin_amdgcn_mfma_f32_16x16x32_bf16(ch1, zhi[tt][1], acc, 0, 0, 0);
                acc = __builtin_amdgcn_mfma_f32_16x16x32_bf16(cl1, zhi[tt][1], acc, 0, 0, 0);
                acc = __builtin_amdgcn_mfma_f32_16x16x32_bf16(ch1, zlo[tt][1], acc, 0, 0, 0);
#pragma unroll
                for (int i = 0; i < 4; ++i) {
                    float u = acc[i];
                    float om1 = m1[tt];
                    bool lt = u < om1;
                    float fm = fminf(m2[tt], u);
                    m2[tt] = lt ? om1 : fm;
                    m1[tt] = lt ? u : om1;
                    bi[tt] = lt ? (cbase + i) : bi[tt];
                }
            }
        }
        if (g < 15) {
            sh_hi[buf ^ 1][tid] = a0; sh_hi[buf ^ 1][tid + 256] = a1;
            sh_lo[buf ^ 1][tid] = b0; sh_lo[buf ^ 1][tid + 256] = b1;
            __syncthreads();
        }
    }

    // in-wave quad merge (lanes l, l^16, l^32, l^48 share a token column)
#pragma unroll
    for (int tt = 0; tt < 2; ++tt) {
        float a1 = m1[tt], a2 = m2[tt];
        int ai = bi[tt];
        {
            float o1 = __shfl_xor(a1, 16); float o2 = __shfl_xor(a2, 16);
            int oi = __shfl_xor(ai, 16);
            top2_merge(a1, a2, ai, o1, o2, oi);
        }
        {
            float o1 = __shfl_xor(a1, 32); float o2 = __shfl_xor(a2, 32);
            int oi = __shfl_xor(ai, 32);
            top2_merge(a1, a2, ai, o1, o2, oi);
        }
        if (quad == 0) {
            const int slot = w * 32 + tt * 16 + col;
            int fl = (a2 - a1) < MARGIN;
            if (fl) {
                unsigned int pos = atomicAdd(flag_count, 1u);
                if (pos >= flag_cap) fl = 0;
                else {
                    flag_list[pos] = t0 + slot;
                    packed_min[pos] = ~0ull;   // lazy init (no memset node)
                }
            }
            s_best[slot] = ai;
            s_flag[slot] = fl;
        }
    }
    __syncthreads();

    // epilogue: 2 threads per token, 32 floats each (r6-verified); flagged deferred
    const int et = tid >> 1, h = tid & 1;
    float loss_t = 0.0f;
    if (!s_flag[et]) {
        const int B = s_best[et];
        const float4* cq  = (const float4*)(cb + (size_t)B * DIM + h * 32);
        const float4* zq4 = (const float4*)(z + (size_t)(t0 + et) * DIM + h * 32);
        float4* o4 = (float4*)(out + (size_t)(t0 + et) * DIM + h * 32);
#pragma unroll
        for (int jj = 0; jj < 8; ++jj) {
#pragma clang fp contract(off)
            float4 cc = cq[jj];
            float4 zz = zq4[jj];
            float d0 = cc.x - zz.x, d1 = cc.y - zz.y;
            float d2 = cc.z - zz.z, d3 = cc.w - zz.w;
            float4 o;
            o.x = zz.x + d0; o.y = zz.y + d1;
            o.z = zz.z + d2; o.w = zz.w + d3;
            o4[jj] = o;
            loss_t = __fmaf_rn(d0, d0, loss_t);
            loss_t = __fmaf_rn(d1, d1, loss_t);
            loss_t = __fmaf_rn(d2, d2, loss_t);
            loss_t = __fmaf_rn(d3, d3, loss_t);
        }
        if (h == 0) out[OUT_IDX_OFF + t0 + et] = (float)B;
    }
#pragma unroll
    for (int off = 32; off > 0; off >>= 1)
        loss_t += __shfl_down(loss_t, off);
    if (lane == 0) atomicAdd(loss_sum, (double)loss_t);
}

__device__ __forceinline__ unsigned long long shfl_down_u64(unsigned long long v, int off) {
    unsigned int lo = (unsigned int)v, hi = (unsigned int)(v >> 32);
    lo = __shfl_down(lo, off);
    hi = __shfl_down(hi, off);
    return ((unsigned long long)hi << 32) | lo;
}

// ---------------------------------------------------------------------------
// Exact numpy-bitwise pass, v4: 16 tokens/group (r10's 64 was serialization-
// bound at ~60 active blocks). Grid 2048 quarter-blocks; ~4x parallelism,
// serial chain /4. Fused finish per group (4th quarter writes outputs; last
// group writes loss). Bitwise arithmetic identical to verified rounds 6-10.
// ---------------------------------------------------------------------------
__global__ __launch_bounds__(256) void vq_exact_min(
    const float* __restrict__ z, const float* __restrict__ cb,
    const float* __restrict__ bnorm,
    const unsigned int* __restrict__ flag_count,
    const int* __restrict__ flag_list,
    unsigned long long* __restrict__ packed_min,
    unsigned int* __restrict__ done_grp, unsigned int* __restrict__ done_all,
    float* __restrict__ out, double* __restrict__ loss_sum,
    unsigned int flag_cap) {
    __shared__ float zsh[TPG * 68];
    __shared__ float szs[TPG];
    __shared__ unsigned int s_old;

    const int tid = threadIdx.x;
    const int w = tid >> 6;
    const int lane = tid & 63;
    unsigned int count = *flag_count;
    if (count > flag_cap) count = flag_cap;
    const unsigned int ngroups = (count + TPG - 1) / TPG;   // <= 512

    if (count == 0) {   // no flagged tokens: block 0 writes the loss
        if (blockIdx.x == 0 && tid == 0) {
            double L = atomicAdd(loss_sum, 0.0);
            out[OUT_LOSS_OFF] = (float)(2.0 * L / (double)((size_t)TOKENS * DIM));
        }
        return;
    }

    const int q = blockIdx.x & 3;
    const unsigned int g = blockIdx.x >> 2;          // 0..511
    if (g >= ngroups) return;

    const int k = q * 256 + w * 64 + lane;           // this lane's code

    float row[DIM];
    {
        const float4* c4 = (const float4*)(cb + (size_t)k * DIM);
#pragma unroll
        for (int j = 0; j < 16; ++j) {
            float4 v = c4[j];
            row[4 * j + 0] = v.x; row[4 * j + 1] = v.y;
            row[4 * j + 2] = v.z; row[4 * j + 3] = v.w;
        }
    }
    const float bnk = bnorm[k];

    {
        const int i = tid >> 2, part = tid & 3;
        if (i < TPG) {
            const unsigned int li = g * TPG + i;
            if (li < count) {
                const int t = flag_list[li];
                const float4* zp = (const float4*)(z + (size_t)t * DIM + part * 16);
                float4* dst = (float4*)(zsh + i * 68 + part * 16);
#pragma unroll
                for (int e = 0; e < 4; ++e) dst[e] = zp[e];
            }
        }
    }
    __syncthreads();
    if (tid < TPG) szs[tid] = np_sumsq64(zsh + tid * 68);
    __syncthreads();

    for (int tt = 0; tt < TPG; ++tt) {
        const unsigned int li = g * TPG + tt;
        const float* zp = zsh + tt * 68;             // wave-uniform -> broadcast
        float l16[16];
#pragma unroll
        for (int g2 = 0; g2 < 4; ++g2) {
            float4 v0 = ((const float4*)(zp + 4 * g2))[0];
            float4 v1 = ((const float4*)(zp + 16 + 4 * g2))[0];
            float4 v2 = ((const float4*)(zp + 32 + 4 * g2))[0];
            float4 v3 = ((const float4*)(zp + 48 + 4 * g2))[0];
            float a0[4] = {v0.x, v0.y, v0.z, v0.w};
            float a1[4] = {v1.x, v1.y, v1.z, v1.w};
            float a2[4] = {v2.x, v2.y, v2.z, v2.w};
            float a3[4] = {v3.x, v3.y, v3.z, v3.w};
#pragma unroll
            for (int e = 0; e < 4; ++e) {
#pragma clang fp contract(off)
                int jj = 4 * g2 + e;
                float acc = a3[e] * row[48 + jj];
                acc = __fmaf_rn(a2[e], row[32 + jj], acc);
                acc = __fmaf_rn(a1[e], row[16 + jj], acc);
                acc = __fmaf_rn(a0[e], row[jj],      acc);
                l16[jj] = acc;
            }
        }
        float e_np;
        {
#pragma clang fp contract(off)
#pragma unroll
            for (int jj = 0; jj < 8; ++jj) l16[jj] = l16[jj] + l16[jj + 8];
#pragma unroll
            for (int jj = 0; jj < 4; ++jj) l16[jj] = l16[jj] + l16[jj + 4];
            l16[0] = l16[0] + l16[2];
            l16[1] = l16[1] + l16[3];
            e_np = l16[0] + l16[1];
        }
        float dd;
        {
#pragma clang fp contract(off)
            float t1 = szs[tt] + bnk;
            float mm = 2.0f * e_np;
            dd = t1 - mm;
        }
        unsigned long long pk =
            ((unsigned long long)__float_as_uint(dd) << 10) | (unsigned int)k;
#pragma unroll
        for (int off = 32; off > 0; off >>= 1) {
            unsigned long long o = shfl_down_u64(pk, off);
            pk = (o < pk) ? o : pk;
        }
        if (lane == 0 && li < count)
            atomicMin(&packed_min[li], pk);
    }

    // ---- fused finish: 4th quarter-block of this group writes outputs ----
    __threadfence();
    __syncthreads();
    if (tid == 0) s_old = atomicAdd(&done_grp[g], 1u);
    __syncthreads();
    if (s_old != 3u) return;
    __threadfence();

    for (int tt = w * (TPG / 4); tt < (w + 1) * (TPG / 4); ++tt) {
        const unsigned int li = g * TPG + tt;
        if (li >= count) break;
        const int t = flag_list[li];
        const unsigned long long pk = atomicAdd(&packed_min[li], 0ull);  // coherent
        const int best = (int)(pk & 1023ull);
        const float zl = zsh[tt * 68 + lane];
        const float zq = cb[(size_t)best * DIM + lane];
        float d, o;
        {
#pragma clang fp contract(off)
            d = zq - zl;
            o = zl + d;
        }
        out[(size_t)t * DIM + lane] = o;
        float l2 = d * d;
#pragma unroll
        for (int off = 32; off > 0; off >>= 1)
            l2 += __shfl_down(l2, off);
        if (lane == 0) {
            out[OUT_IDX_OFF + t] = (float)best;
            atomicAdd(loss_sum, (double)l2);
        }
    }

    __threadfence();
    __syncthreads();
    if (tid == 0) {
        unsigned int old = atomicAdd(done_all, 1u);
        if (old == ngroups - 1) {
            double L = atomicAdd(loss_sum, 0.0);   // coherent read-through
            out[OUT_LOSS_OFF] = (float)(2.0 * L / (double)((size_t)TOKENS * DIM));
        }
    }
}

extern "C" void kernel_launch(void* const* d_in, const int* in_sizes, int n_in,
                              void* d_out, int out_size, void* d_ws, size_t ws_size,
                              hipStream_t stream) {
    const float* z  = (const float*)d_in[0];   // [8,8192,64] f32
    const float* cb = (const float*)d_in[1];   // [1024,64] f32
    float* out = (float*)d_out;

    char* ws = (char*)d_ws;
    double* loss_sum = (double*)(ws + WS_LOSS);
    unsigned int* flag_count = (unsigned int*)(ws + WS_FLAGC);
    unsigned int* done_all = (unsigned int*)(ws + WS_DONEA);
    unsigned int* done_grp = (unsigned int*)(ws + WS_DGRP);
    float* bnorm = (float*)(ws + WS_BNORM);
    unsigned short* chi = (unsigned short*)(ws + WS_CHI);
    unsigned short* clo = (unsigned short*)(ws + WS_CLO);
    unsigned long long* packed = (unsigned long long*)(ws + WS_PACKED);
    int* flag_list = (int*)(ws + WS_FLAGS);

    unsigned int cap = 0;
    if (ws_size > WS_FLAGS + 4) {
        size_t c = (ws_size - WS_FLAGS) / 4;
        cap = (c > FLAG_CAP) ? FLAG_CAP : (unsigned int)c;
    }

    vq_prep<<<dim3(256), dim3(256), 0, stream>>>(
        cb, chi, clo, bnorm, (unsigned int*)ws);
    vq_fast<<<dim3(TOKENS / 128), dim3(256), 0, stream>>>(
        z, cb, chi, clo, bnorm, out, flag_count, flag_list, packed, loss_sum, cap);
    vq_exact_min<<<dim3(2048), dim3(256), 0, stream>>>(
        z, cb, bnorm, flag_count, flag_list, packed, done_grp, done_all,
        out, loss_sum, cap);
}